// Round 6
// baseline (710.426 us; speedup 1.0000x reference)
//
#include <hip/hip_runtime.h>
#include <hip/hip_fp16.h>

// Swin-V2 window attention, fully fused, MI355X (gfx950).
// Round 6: R5 structure (1 barrier/head, parity kh/vT/krs, reg-accum proj)
// with the register cap raised: __launch_bounds__(256,3) -> ~168 VGPR/wave,
// 3 blocks/CU. R4/R5 spilled because (256,4)=128 regs starved the arch side
// (VGPR_Count=64 + 374 MB scratch writes). Paired ct MFMA chains restored.

#define NTOK 49
#define DIM 192
#define NH 6
#define BATCH 4096

typedef __attribute__((ext_vector_type(4))) float f32x4;
typedef __attribute__((ext_vector_type(8))) _Float16 f16x8;
typedef __attribute__((ext_vector_type(4))) _Float16 f16x4h;

// ws layout (bytes)
#define W1_OFF 0                        // [576][192] f16
#define W2_OFF 221184                   // [192][192] f16
#define BMI_OFF 294912                  // [64*6][49(i) x 52] f16 (+slack)
#define HSC_OFF 2260992                 // [6] f32 head scales

#define MFMA16(a, b, c) __builtin_amdgcn_mfma_f32_16x16x32_f16(a, b, c, 0, 0, 0)

__global__ __launch_bounds__(256) void k_setup(
    const float* __restrict__ qkv_w, const float* __restrict__ proj_w,
    const float* __restrict__ mask, const float* __restrict__ table,
    const int* __restrict__ rel_index, const float* __restrict__ ls,
    _Float16* __restrict__ W1, _Float16* __restrict__ W2,
    _Float16* __restrict__ bmi, float* __restrict__ hsc) {
  int idx = blockIdx.x * 256 + threadIdx.x;
  if (idx < 576 * 192) W1[idx] = (_Float16)qkv_w[idx];
  if (idx < 192 * 192) W2[idx] = (_Float16)proj_w[idx];
  if (idx < NH) hsc[idx] = __expf(fminf(ls[idx], 4.60517019f));
  if (idx < 64 * NH * 2401) {
    int p = idx / 2401, rem = idx % 2401;
    int i = rem / 49, j = rem % 49;     // stored [p][i (stride 52)][j]
    int wdx = p / NH, h = p % NH;
    bmi[(size_t)p * 2548 + i * 52 + j] =
        (_Float16)(table[rel_index[i * 49 + j] * NH + h] +
                   mask[wdx * 2401 + i * 49 + j]);
  }
}

__global__ __launch_bounds__(256, 3) void k_fused(
    const float* __restrict__ x, const _Float16* __restrict__ W1,
    const float* __restrict__ qkv_b, const _Float16* __restrict__ bmi,
    const float* __restrict__ hsc, const _Float16* __restrict__ W2,
    const float* __restrict__ proj_b, float* __restrict__ out) {
  __shared__ __align__(16) char smem[29440];
  _Float16* qh = (_Float16*)smem;            // [64][72] f16 (Q cols 0..32; P alias)
  _Float16* kh = (_Float16*)(smem + 9216);   // [2][64][40] f16 (idle buf = O_h scratch)
  _Float16* vT = (_Float16*)(smem + 19456);  // [2][32][72] f16 (v transposed)
  float* qrs = (float*)(smem + 28672);       // [64]    rsqrt(|q|^2)*scale
  float* krs = (float*)(smem + 28928);       // [2][64] rsqrt(|k|^2)

  const int b = blockIdx.x;
  const int tid = threadIdx.x;
  const int lane = tid & 63;
  const int w = tid >> 6;  // wave id = M row-tile
  const int L = lane & 15;
  const int g = lane >> 4;
  const int row0 = 16 * w + 4 * g;

  // ---- x A-fragments: rows 16w+L (zero past 49), k = 32kf + 8g .. +8 ----
  f16x8 ax[6];
  {
    const int row = 16 * w + L;
    const float* xr = x + ((size_t)b * NTOK + (row < NTOK ? row : 0)) * DIM + 8 * g;
    const f32x4 vz = {0.f, 0.f, 0.f, 0.f};
#pragma unroll
    for (int kf = 0; kf < 6; ++kf) {
      f32x4 lo = *(const f32x4*)(xr + 32 * kf);
      f32x4 hi = *(const f32x4*)(xr + 32 * kf + 4);
      if (row >= NTOK) { lo = vz; hi = vz; }
      f16x8 v;
      v[0] = (_Float16)lo[0]; v[1] = (_Float16)lo[1];
      v[2] = (_Float16)lo[2]; v[3] = (_Float16)lo[3];
      v[4] = (_Float16)hi[0]; v[5] = (_Float16)hi[1];
      v[6] = (_Float16)hi[2]; v[7] = (_Float16)hi[3];
      ax[kf] = v;
    }
  }

  f32x4 acc_out[12];
#pragma unroll
  for (int ct = 0; ct < 12; ++ct) acc_out[ct] = (f32x4){0.f, 0.f, 0.f, 0.f};

  const _Float16* bmi_b =
      bmi + (size_t)(b & 63) * NH * 2548 + (16 * w + L) * 52;

#pragma unroll 1
  for (int h = 0; h < NH; ++h) {
    const int ph = h & 1;
    _Float16* khp = kh + ph * 2560;        // this head's K
    _Float16* vTp = vT + ph * 2304;        // this head's V^T
    _Float16* ob = kh + (ph ^ 1) * 2560;   // idle parity buf = O_h scratch
    float* krp = krs + ph * 64;
    const float hs = hsc[h];

    // prefetch bias+mask rows (global/L2; consumed in softmax, hides under QKV)
    f16x4h bm4[4];
    {
      const _Float16* bp = bmi_b + (size_t)h * 2548 + 4 * g;
#pragma unroll
      for (int t = 0; t < 4; ++t) bm4[t] = *(const f16x4h*)(bp + 16 * t);
    }

    // ---- per-head QKV GEMM: q->qh, k->khp, v->vTp (transposed) ----
    float ssq[4] = {0.f, 0.f, 0.f, 0.f}, ssk[4] = {0.f, 0.f, 0.f, 0.f};
#pragma unroll
    for (int s = 0; s < 3; ++s) {
      const int col0 = s * DIM + 32 * h + L;
      const _Float16* wp0 = W1 + (size_t)col0 * DIM + 8 * g;
      f16x8 wf0[6], wf1[6];
#pragma unroll
      for (int kf = 0; kf < 6; ++kf) {
        wf0[kf] = *(const f16x8*)(wp0 + 32 * kf);
        wf1[kf] = *(const f16x8*)(wp0 + 16 * DIM + 32 * kf);
      }
      f32x4 a0 = {0.f, 0.f, 0.f, 0.f}, a1 = {0.f, 0.f, 0.f, 0.f};
#pragma unroll
      for (int kf = 0; kf < 6; ++kf) {
        a0 = MFMA16(ax[kf], wf0[kf], a0);
        a1 = MFMA16(ax[kf], wf1[kf], a1);
      }
      const float b0 = qkv_b[col0], b1 = qkv_b[col0 + 16];
      if (s == 0) {
#pragma unroll
        for (int r = 0; r < 4; ++r) {
          float v0 = a0[r] + b0, v1 = a1[r] + b1;
          qh[(row0 + r) * 72 + L] = (_Float16)v0;
          qh[(row0 + r) * 72 + 16 + L] = (_Float16)v1;
          ssq[r] += v0 * v0 + v1 * v1;
        }
      } else if (s == 1) {
#pragma unroll
        for (int r = 0; r < 4; ++r) {
          float v0 = a0[r] + b0, v1 = a1[r] + b1;
          khp[(row0 + r) * 40 + L] = (_Float16)v0;
          khp[(row0 + r) * 40 + 16 + L] = (_Float16)v1;
          ssk[r] += v0 * v0 + v1 * v1;
        }
      } else {
        f16x4h p0, p1;
#pragma unroll
        for (int r = 0; r < 4; ++r) {
          p0[r] = (_Float16)(a0[r] + b0);
          p1[r] = (_Float16)(a1[r] + b1);
        }
        *(f16x4h*)(vTp + L * 72 + row0) = p0;         // vT[d=L][n]
        *(f16x4h*)(vTp + (16 + L) * 72 + row0) = p1;  // vT[d=16+L][n]
      }
    }
#pragma unroll
    for (int r = 0; r < 4; ++r) {
      float sq = ssq[r], sk = ssk[r];
      sq += __shfl_xor(sq, 1); sq += __shfl_xor(sq, 2);
      sq += __shfl_xor(sq, 4); sq += __shfl_xor(sq, 8);
      sk += __shfl_xor(sk, 1); sk += __shfl_xor(sk, 2);
      sk += __shfl_xor(sk, 4); sk += __shfl_xor(sk, 8);
      if (L == 0) {
        qrs[row0 + r] = rsqrtf(fmaxf(sq, 1e-24f)) * hs;
        krp[row0 + r] = rsqrtf(fmaxf(sk, 1e-24f));
      }
    }
    __syncthreads();  // the ONLY barrier per head

    // ---- S^T = K·Q : thread holds S[i=16w+L][j=16t+4g+r] ----
    f16x8 bq = *(const f16x8*)(qh + (16 * w + L) * 72 + 8 * g);
    f32x4 st[4];
#pragma unroll
    for (int t = 0; t < 4; ++t) {
      f16x8 ak = *(const f16x8*)(khp + (16 * t + L) * 40 + 8 * g);
      f32x4 z = {0.f, 0.f, 0.f, 0.f};
      st[t] = MFMA16(ak, bq, z);
    }
    const float qr = qrs[16 * w + L];

    // ---- softmax over j, fully in-register ----
    float p[4][4];
#pragma unroll
    for (int t = 0; t < 4; ++t) {
      f32x4 kv = *(const f32x4*)(krp + 16 * t + 4 * g);
#pragma unroll
      for (int r = 0; r < 4; ++r) {
        int j = 16 * t + 4 * g + r;
        p[t][r] = (j < NTOK) ? fmaf(st[t][r], qr * kv[r], (float)bm4[t][r])
                             : -1e30f;
      }
    }
    float mx = p[0][0];
#pragma unroll
    for (int t = 0; t < 4; ++t)
#pragma unroll
      for (int r = 0; r < 4; ++r) mx = fmaxf(mx, p[t][r]);
    mx = fmaxf(mx, __shfl_xor(mx, 16));
    mx = fmaxf(mx, __shfl_xor(mx, 32));
    float sum = 0.f;
#pragma unroll
    for (int t = 0; t < 4; ++t)
#pragma unroll
      for (int r = 0; r < 4; ++r) {
        p[t][r] = __expf(p[t][r] - mx);
        sum += p[t][r];
      }
    sum += __shfl_xor(sum, 16);
    sum += __shfl_xor(sum, 32);
    const float is = 1.0f / sum;

    // ---- write normalized P into qh alias (own rows, after bq read) ----
#pragma unroll
    for (int t = 0; t < 4; ++t) {
      f16x4h pk;
#pragma unroll
      for (int r = 0; r < 4; ++r) pk[r] = (_Float16)(p[t][r] * is);
      *(f16x4h*)(qh + (16 * w + L) * 72 + 16 * t + 4 * g) = pk;
    }

    // ---- PV: O[i][d] = sum_j P[i][j] vT[d][j] (same-wave LDS RAW) ----
    f16x8 pa0 = *(const f16x8*)(qh + (16 * w + L) * 72 + 8 * g);
    f16x8 pa1 = *(const f16x8*)(qh + (16 * w + L) * 72 + 32 + 8 * g);
#pragma unroll
    for (int dt = 0; dt < 2; ++dt) {
      f16x8 bv0 = *(const f16x8*)(vTp + (16 * dt + L) * 72 + 8 * g);
      f16x8 bv1 = *(const f16x8*)(vTp + (16 * dt + L) * 72 + 32 + 8 * g);
      f32x4 o4 = {0.f, 0.f, 0.f, 0.f};
      o4 = MFMA16(pa0, bv0, o4);
      o4 = MFMA16(pa1, bv1, o4);
#pragma unroll
      for (int r = 0; r < 4; ++r)
        ob[(row0 + r) * 40 + 16 * dt + L] = (_Float16)o4[r];
    }

    // ---- proj partial: acc_out += O_h @ W2[:,32h:32h+32]^T ----
    f16x8 aa = *(const f16x8*)(ob + (16 * w + L) * 40 + 8 * g);
#pragma unroll
    for (int ct = 0; ct < 12; ++ct) {
      f16x8 w2f = *(const f16x8*)(W2 + (size_t)(16 * ct + L) * DIM + 32 * h + 8 * g);
      acc_out[ct] = MFMA16(aa, w2f, acc_out[ct]);
    }
  }

  // ---- epilogue: out = acc_out + proj_b ----
#pragma unroll
  for (int ct = 0; ct < 12; ++ct) {
    const float pb_ = proj_b[16 * ct + L];
#pragma unroll
    for (int r = 0; r < 4; ++r) {
      int row = row0 + r;
      if (row < NTOK)
        out[((size_t)b * NTOK + row) * DIM + 16 * ct + L] = acc_out[ct][r] + pb_;
    }
  }
}

extern "C" void kernel_launch(void* const* d_in, const int* in_sizes, int n_in,
                              void* d_out, int out_size, void* d_ws, size_t ws_size,
                              hipStream_t stream) {
  const float* x     = (const float*)d_in[0];
  const float* mask  = (const float*)d_in[1];
  const float* qkv_w = (const float*)d_in[2];
  const float* qkv_b = (const float*)d_in[3];
  const float* ls    = (const float*)d_in[4];
  const float* tbl   = (const float*)d_in[5];
  const int*   ridx  = (const int*)d_in[6];
  const float* pw    = (const float*)d_in[7];
  const float* pb    = (const float*)d_in[8];
  float* out = (float*)d_out;
  char* ws = (char*)d_ws;

  _Float16* W1 = (_Float16*)(ws + W1_OFF);
  _Float16* W2 = (_Float16*)(ws + W2_OFF);
  _Float16* bmi = (_Float16*)(ws + BMI_OFF);
  float* hsc = (float*)(ws + HSC_OFF);

  hipLaunchKernelGGL(k_setup, dim3(3602), dim3(256), 0, stream,
                     qkv_w, pw, mask, tbl, ridx, ls, W1, W2, bmi, hsc);
  hipLaunchKernelGGL(k_fused, dim3(BATCH), dim3(256), 0, stream,
                     x, W1, qkv_b, bmi, hsc, W2, pb, out);
}

// Round 7
// 399.318 us; speedup vs baseline: 1.7791x; 1.7791x over previous
//
#include <hip/hip_runtime.h>
#include <hip/hip_fp16.h>

// Swin-V2 window attention, MI355X (gfx950). Round 7: two-kernel split.
// k_qkv: x @ W1^T GEMM (paired col-tiles, (256,3)) -> q,k [B][H][49][32] f16,
//        v TRANSPOSED [B][H][32][56] f16.
// k_attn2: wave = head. Q/K/V frags direct from global, in-register cosine
//        norms + softmax, P through wave-private LDS, ONE barrier, fused proj.

#define NTOK 49
#define DIM 192
#define NH 6
#define BATCH 4096
#define MTOT 200704  // BATCH*NTOK

typedef __attribute__((ext_vector_type(4))) float f32x4;
typedef __attribute__((ext_vector_type(8))) _Float16 f16x8;
typedef __attribute__((ext_vector_type(4))) _Float16 f16x4h;

// ws layout (bytes)
#define W1_OFF 0                 // [576][192] f16
#define W2_OFF 221184            // [192][192] f16
#define BMI_OFF 294912           // [64*6][49 x 52] f16 (+slack)
#define HSC_OFF 2260992          // [6] f32
#define Q_OFF 4194304            // [B][6][49][32] f16 = 77.1 MB
#define K_OFF 81264640           // same
#define VT_OFF 158334976         // [B][6][32][56] f16 = 88.1 MB (end ~246.4MB)

#define MFMA16(a, b, c) __builtin_amdgcn_mfma_f32_16x16x32_f16(a, b, c, 0, 0, 0)

__global__ __launch_bounds__(256) void k_setup(
    const float* __restrict__ qkv_w, const float* __restrict__ proj_w,
    const float* __restrict__ mask, const float* __restrict__ table,
    const int* __restrict__ rel_index, const float* __restrict__ ls,
    _Float16* __restrict__ W1, _Float16* __restrict__ W2,
    _Float16* __restrict__ bmi, float* __restrict__ hsc) {
  int idx = blockIdx.x * 256 + threadIdx.x;
  if (idx < 576 * 192) W1[idx] = (_Float16)qkv_w[idx];
  if (idx < 192 * 192) W2[idx] = (_Float16)proj_w[idx];
  if (idx < NH) hsc[idx] = __expf(fminf(ls[idx], 4.60517019f));
  if (idx < 64 * NH * 2401) {
    int p = idx / 2401, rem = idx % 2401;
    int i = rem / 49, j = rem % 49;  // stored [p][i (stride 52)][j]
    int wdx = p / NH, h = p % NH;
    bmi[(size_t)p * 2548 + i * 52 + j] =
        (_Float16)(table[rel_index[i * 49 + j] * NH + h] +
                   mask[wdx * 2401 + i * 49 + j]);
  }
}

// ---------------- QKV GEMM ----------------
__global__ __launch_bounds__(256, 3) void k_qkv(
    const float* __restrict__ x, const _Float16* __restrict__ W1,
    const float* __restrict__ qkv_b, _Float16* __restrict__ q16,
    _Float16* __restrict__ k16, _Float16* __restrict__ vt16) {
  const int lane = threadIdx.x & 63;
  const int w = threadIdx.x >> 6;
  const int rowbase = blockIdx.x * 128 + w * 32;
  const int L = lane & 15;
  const int g = lane >> 4;

  // A fragments: 2 row-tiles x 6 K-frags
  f16x8 ax[2][6];
#pragma unroll
  for (int rt = 0; rt < 2; ++rt) {
    const float* xr = x + (size_t)(rowbase + rt * 16 + L) * DIM + 8 * g;
#pragma unroll
    for (int kf = 0; kf < 6; ++kf) {
      f32x4 lo = *(const f32x4*)(xr + 32 * kf);
      f32x4 hi = *(const f32x4*)(xr + 32 * kf + 4);
      f16x8 v;
      v[0] = (_Float16)lo[0]; v[1] = (_Float16)lo[1];
      v[2] = (_Float16)lo[2]; v[3] = (_Float16)lo[3];
      v[4] = (_Float16)hi[0]; v[5] = (_Float16)hi[1];
      v[6] = (_Float16)hi[2]; v[7] = (_Float16)hi[3];
      ax[rt][kf] = v;
    }
  }
  // row meta: (b, n) and bases for q/k and vT layouts
  int qkb[2][4], vtb[2][4];
#pragma unroll
  for (int rt = 0; rt < 2; ++rt)
#pragma unroll
    for (int r = 0; r < 4; ++r) {
      int row = rowbase + rt * 16 + 4 * g + r;
      int bb = row / 49, n = row - bb * 49;
      qkb[rt][r] = bb * 9408 + n * 32;   // (b*6+h)*49+n)*32 = b*9408+h*1568+n*32+d
      vtb[rt][r] = bb * 10752 + n;       // (b*6+h)*32+d)*56+n = b*10752+h*1792+d*56+n
    }

#pragma unroll 1
  for (int t = 0; t < 18; ++t) {
    const int col0 = 32 * t + L;
    const _Float16* wp = W1 + (size_t)col0 * DIM + 8 * g;
    f16x8 wf0[6], wf1[6];
#pragma unroll
    for (int kf = 0; kf < 6; ++kf) {
      wf0[kf] = *(const f16x8*)(wp + 32 * kf);
      wf1[kf] = *(const f16x8*)(wp + 16 * DIM + 32 * kf);
    }
    f32x4 acc[2][2];
    acc[0][0] = (f32x4){0.f, 0.f, 0.f, 0.f}; acc[0][1] = acc[0][0];
    acc[1][0] = acc[0][0]; acc[1][1] = acc[0][0];
#pragma unroll
    for (int kf = 0; kf < 6; ++kf) {
      acc[0][0] = MFMA16(ax[0][kf], wf0[kf], acc[0][0]);
      acc[1][0] = MFMA16(ax[1][kf], wf0[kf], acc[1][0]);
      acc[0][1] = MFMA16(ax[0][kf], wf1[kf], acc[0][1]);
      acc[1][1] = MFMA16(ax[1][kf], wf1[kf], acc[1][1]);
    }
#pragma unroll
    for (int ct = 0; ct < 2; ++ct) {
      const int col = col0 + 16 * ct;
      const int s = col / 192;
      const int c2 = col - s * 192;
      const int hh = c2 >> 5, d = c2 & 31;
      const float bias = qkv_b[col];
      if (s == 0) {
        const int off = hh * 1568 + d;
#pragma unroll
        for (int rt = 0; rt < 2; ++rt)
#pragma unroll
          for (int r = 0; r < 4; ++r)
            q16[qkb[rt][r] + off] = (_Float16)(acc[rt][ct][r] + bias);
      } else if (s == 1) {
        const int off = hh * 1568 + d;
#pragma unroll
        for (int rt = 0; rt < 2; ++rt)
#pragma unroll
          for (int r = 0; r < 4; ++r)
            k16[qkb[rt][r] + off] = (_Float16)(acc[rt][ct][r] + bias);
      } else {
        const int off = hh * 1792 + d * 56;
#pragma unroll
        for (int rt = 0; rt < 2; ++rt)
#pragma unroll
          for (int r = 0; r < 4; ++r)
            vt16[vtb[rt][r] + off] = (_Float16)(acc[rt][ct][r] + bias);
      }
    }
  }
}

// ---------------- attention + proj, wave = head ----------------
__global__ __launch_bounds__(384, 4) void k_attn2(
    const _Float16* __restrict__ q16, const _Float16* __restrict__ k16,
    const _Float16* __restrict__ vt16, const _Float16* __restrict__ bmi,
    const float* __restrict__ hsc, const _Float16* __restrict__ W2,
    const float* __restrict__ proj_b, float* __restrict__ out) {
  __shared__ __align__(16) _Float16 pl[6][16 * 72];  // per-wave P-hat
  __shared__ __align__(16) _Float16 ao[64 * 200];    // O staging [row][192+pad]

  const int b = blockIdx.x;
  const int tid = threadIdx.x;
  const int h = tid >> 6;
  const int lane = tid & 63;
  const int L = lane & 15;
  const int g = lane >> 4;

  const size_t qoff = ((size_t)b * NH + h) * 1568;  // 49*32
  const size_t voff = ((size_t)b * NH + h) * 1792;  // 32*56
  const float hs = hsc[h];

  // K A-frags (4 j-tiles) + V^T B-frags (2 dt x 2 kf), direct from global
  f16x8 kf4[4];
#pragma unroll
  for (int jt = 0; jt < 4; ++jt) {
    int jrow = 16 * jt + L; if (jrow > 48) jrow = 48;  // clamp (masked later)
    kf4[jt] = *(const f16x8*)(k16 + qoff + jrow * 32 + 8 * g);
  }
  f16x8 vf[2][2];
#pragma unroll
  for (int dt = 0; dt < 2; ++dt)
#pragma unroll
    for (int kf = 0; kf < 2; ++kf) {
      int joff = 32 * kf + 8 * g; if (joff > 48) joff = 48;  // stay in-bounds (x0)
      vf[dt][kf] = *(const f16x8*)(vt16 + voff + (16 * dt + L) * 56 + joff);
    }

  // |k|^2 per j-row -> krr[jt][r] aligned to softmax lanes
  float krr[4][4];
#pragma unroll
  for (int jt = 0; jt < 4; ++jt) {
    float kk = 0.f;
#pragma unroll
    for (int e = 0; e < 8; ++e) kk += (float)kf4[jt][e] * (float)kf4[jt][e];
    kk += __shfl_xor(kk, 16);
    kk += __shfl_xor(kk, 32);
#pragma unroll
    for (int r = 0; r < 4; ++r)
      krr[jt][r] = rsqrtf(fmaxf(__shfl(kk, 4 * g + r, 64), 1e-24f));
  }

  _Float16* plw = &pl[h][0];
  const _Float16* bmp = bmi + ((size_t)(b & 63) * NH + h) * 2548;

#pragma unroll 1
  for (int it = 0; it < 4; ++it) {
    int irow = 16 * it + L; if (irow > 48) irow = 48;  // clamp (write-masked)
    f16x8 qf = *(const f16x8*)(q16 + qoff + irow * 32 + 8 * g);
    float qq = 0.f;
#pragma unroll
    for (int e = 0; e < 8; ++e) qq += (float)qf[e] * (float)qf[e];
    qq += __shfl_xor(qq, 16);
    qq += __shfl_xor(qq, 32);
    const float qr = rsqrtf(fmaxf(qq, 1e-24f)) * hs;

    f32x4 st[4];
#pragma unroll
    for (int jt = 0; jt < 4; ++jt) {
      f32x4 z = {0.f, 0.f, 0.f, 0.f};
      st[jt] = MFMA16(kf4[jt], qf, z);
    }
    // bias+mask rows for i = 16it+L
    const _Float16* bp = bmp + (16 * it + L) * 52 + 4 * g;
    float p[4][4];
#pragma unroll
    for (int jt = 0; jt < 4; ++jt) {
      f16x4h bm4 = *(const f16x4h*)(bp + 16 * jt);
#pragma unroll
      for (int r = 0; r < 4; ++r) {
        int j = 16 * jt + 4 * g + r;
        p[jt][r] = (j < NTOK)
                       ? fmaf(st[jt][r], qr * krr[jt][r], (float)bm4[r])
                       : -1e30f;
      }
    }
    float mx = p[0][0];
#pragma unroll
    for (int jt = 0; jt < 4; ++jt)
#pragma unroll
      for (int r = 0; r < 4; ++r) mx = fmaxf(mx, p[jt][r]);
    mx = fmaxf(mx, __shfl_xor(mx, 16));
    mx = fmaxf(mx, __shfl_xor(mx, 32));
    float sum = 0.f;
#pragma unroll
    for (int jt = 0; jt < 4; ++jt)
#pragma unroll
      for (int r = 0; r < 4; ++r) {
        p[jt][r] = __expf(p[jt][r] - mx);
        sum += p[jt][r];
      }
    sum += __shfl_xor(sum, 16);
    sum += __shfl_xor(sum, 32);
    const float is = 1.0f / sum;

#pragma unroll
    for (int jt = 0; jt < 4; ++jt) {
      f16x4h pk;
#pragma unroll
      for (int r = 0; r < 4; ++r) pk[r] = (_Float16)(p[jt][r] * is);
      *(f16x4h*)(plw + L * 72 + 16 * jt + 4 * g) = pk;
    }
    // PV for these 16 i-rows
    f16x8 pa0 = *(const f16x8*)(plw + L * 72 + 8 * g);
    f16x8 pa1 = *(const f16x8*)(plw + L * 72 + 32 + 8 * g);
#pragma unroll
    for (int dt = 0; dt < 2; ++dt) {
      f32x4 o4 = {0.f, 0.f, 0.f, 0.f};
      o4 = MFMA16(pa0, vf[dt][0], o4);
      o4 = MFMA16(pa1, vf[dt][1], o4);
#pragma unroll
      for (int r = 0; r < 4; ++r)
        ao[(16 * it + 4 * g + r) * 200 + 32 * h + 16 * dt + L] = (_Float16)o4[r];
    }
  }
  __syncthreads();  // the ONLY barrier

  // proj: wave handles col-tiles {h, h+6}
#pragma unroll
  for (int cp = 0; cp < 2; ++cp) {
    const int ct = h + 6 * cp;
    const _Float16* wp = W2 + (size_t)(16 * ct + L) * DIM + 8 * g;
    f16x8 wfr[6];
#pragma unroll
    for (int kf = 0; kf < 6; ++kf) wfr[kf] = *(const f16x8*)(wp + 32 * kf);
    const float pbv = proj_b[16 * ct + L];
#pragma unroll 1
    for (int mt = 0; mt < 4; ++mt) {
      f32x4 acc = {0.f, 0.f, 0.f, 0.f};
#pragma unroll
      for (int kf = 0; kf < 6; ++kf) {
        f16x8 af = *(const f16x8*)(ao + (16 * mt + L) * 200 + 32 * kf + 8 * g);
        acc = MFMA16(af, wfr[kf], acc);
      }
#pragma unroll
      for (int r = 0; r < 4; ++r) {
        int row = 16 * mt + 4 * g + r;
        if (row < NTOK)
          out[((size_t)b * NTOK + row) * DIM + 16 * ct + L] = acc[r] + pbv;
      }
    }
  }
}

extern "C" void kernel_launch(void* const* d_in, const int* in_sizes, int n_in,
                              void* d_out, int out_size, void* d_ws, size_t ws_size,
                              hipStream_t stream) {
  const float* x     = (const float*)d_in[0];
  const float* mask  = (const float*)d_in[1];
  const float* qkv_w = (const float*)d_in[2];
  const float* qkv_b = (const float*)d_in[3];
  const float* ls    = (const float*)d_in[4];
  const float* tbl   = (const float*)d_in[5];
  const int*   ridx  = (const int*)d_in[6];
  const float* pw    = (const float*)d_in[7];
  const float* pb    = (const float*)d_in[8];
  float* out = (float*)d_out;
  char* ws = (char*)d_ws;

  _Float16* W1 = (_Float16*)(ws + W1_OFF);
  _Float16* W2 = (_Float16*)(ws + W2_OFF);
  _Float16* bmi = (_Float16*)(ws + BMI_OFF);
  float* hsc = (float*)(ws + HSC_OFF);
  _Float16* q16 = (_Float16*)(ws + Q_OFF);
  _Float16* k16 = (_Float16*)(ws + K_OFF);
  _Float16* vt16 = (_Float16*)(ws + VT_OFF);

  hipLaunchKernelGGL(k_setup, dim3(3602), dim3(256), 0, stream,
                     qkv_w, pw, mask, tbl, ridx, ls, W1, W2, bmi, hsc);
  hipLaunchKernelGGL(k_qkv, dim3(MTOT / 128), dim3(256), 0, stream,
                     x, W1, qkv_b, q16, k16, vt16);
  hipLaunchKernelGGL(k_attn2, dim3(BATCH), dim3(384), 0, stream,
                     q16, k16, vt16, bmi, hsc, W2, pb, out);
}

// Round 8
// 307.960 us; speedup vs baseline: 2.3069x; 1.2967x over previous
//
#include <hip/hip_runtime.h>
#include <hip/hip_fp16.h>

// Swin-V2 window attention, MI355X (gfx950). Round 8.
// k_qkv v2: W1 staged through double-buffered LDS (XOR-swizzled, 1 barrier
//   per 32-col K-step, issue-early/write-late staging) -> kills the exposed
//   L2 latency that made R7's k_qkv 290us (MfmaUtil 6%).
// k_attn2: unchanged from R7 (wave=head, direct global frags, 1 barrier).

#define NTOK 49
#define DIM 192
#define NH 6
#define BATCH 4096
#define MTOT 200704  // BATCH*NTOK

typedef __attribute__((ext_vector_type(4))) float f32x4;
typedef __attribute__((ext_vector_type(8))) _Float16 f16x8;
typedef __attribute__((ext_vector_type(4))) _Float16 f16x4h;

// ws layout (bytes)
#define W1_OFF 0                 // [576][192] f16
#define W2_OFF 221184            // [192][192] f16
#define BMI_OFF 294912           // [64*6][49 x 52] f16 (+slack)
#define HSC_OFF 2260992          // [6] f32
#define Q_OFF 4194304            // [B][6][49][32] f16 = 77.1 MB
#define K_OFF 81264640           // same
#define VT_OFF 158334976         // [B][6][32][56] f16 = 88.1 MB (end ~246.4MB)

#define MFMA16(a, b, c) __builtin_amdgcn_mfma_f32_16x16x32_f16(a, b, c, 0, 0, 0)

__global__ __launch_bounds__(256) void k_setup(
    const float* __restrict__ qkv_w, const float* __restrict__ proj_w,
    const float* __restrict__ mask, const float* __restrict__ table,
    const int* __restrict__ rel_index, const float* __restrict__ ls,
    _Float16* __restrict__ W1, _Float16* __restrict__ W2,
    _Float16* __restrict__ bmi, float* __restrict__ hsc) {
  int idx = blockIdx.x * 256 + threadIdx.x;
  if (idx < 576 * 192) W1[idx] = (_Float16)qkv_w[idx];
  if (idx < 192 * 192) W2[idx] = (_Float16)proj_w[idx];
  if (idx < NH) hsc[idx] = __expf(fminf(ls[idx], 4.60517019f));
  if (idx < 64 * NH * 2401) {
    int p = idx / 2401, rem = idx % 2401;
    int i = rem / 49, j = rem % 49;  // stored [p][i (stride 52)][j]
    int wdx = p / NH, h = p % NH;
    bmi[(size_t)p * 2548 + i * 52 + j] =
        (_Float16)(table[rel_index[i * 49 + j] * NH + h] +
                   mask[wdx * 2401 + i * 49 + j]);
  }
}

// ---------------- QKV GEMM, LDS-staged W1 ----------------
__global__ __launch_bounds__(256, 3) void k_qkv(
    const float* __restrict__ x, const _Float16* __restrict__ W1,
    const float* __restrict__ qkv_b, _Float16* __restrict__ q16,
    _Float16* __restrict__ k16, _Float16* __restrict__ vt16) {
  __shared__ __align__(16) char wlds[2][12288];  // 32-col W1 tile, swizzled

  const int tid = threadIdx.x;
  const int lane = tid & 63;
  const int w = tid >> 6;
  const int rowbase = blockIdx.x * 128 + w * 32;
  const int L = lane & 15;
  const int g = lane >> 4;

  // A fragments: 2 row-tiles x 6 K-frags (f32 x -> f16)
  f16x8 ax[2][6];
#pragma unroll
  for (int rt = 0; rt < 2; ++rt) {
    const float* xr = x + (size_t)(rowbase + rt * 16 + L) * DIM + 8 * g;
#pragma unroll
    for (int kf = 0; kf < 6; ++kf) {
      f32x4 lo = *(const f32x4*)(xr + 32 * kf);
      f32x4 hi = *(const f32x4*)(xr + 32 * kf + 4);
      f16x8 v;
      v[0] = (_Float16)lo[0]; v[1] = (_Float16)lo[1];
      v[2] = (_Float16)lo[2]; v[3] = (_Float16)lo[3];
      v[4] = (_Float16)hi[0]; v[5] = (_Float16)hi[1];
      v[6] = (_Float16)hi[2]; v[7] = (_Float16)hi[3];
      ax[rt][kf] = v;
    }
  }
  // row meta for q/k (row-major) and vT (transposed) stores
  int qkb[2][4], vtb[2][4];
#pragma unroll
  for (int rt = 0; rt < 2; ++rt)
#pragma unroll
    for (int r = 0; r < 4; ++r) {
      int row = rowbase + rt * 16 + 4 * g + r;
      int bb = row / 49, n = row - bb * 49;
      qkb[rt][r] = bb * 9408 + n * 32;  // + h*1568 + d
      vtb[rt][r] = bb * 10752 + n;      // + h*1792 + d*56
    }

  const uint32_t so = (uint32_t)tid * 16;  // staging offset (per thread 3x16B)

  // ---- prologue: stage tile 0 into buf 0 ----
  {
    f16x8 stg[3];
#pragma unroll
    for (int p_ = 0; p_ < 3; ++p_)
      stg[p_] = *(const f16x8*)((const char*)W1 + p_ * 4096 + so);
#pragma unroll
    for (int p_ = 0; p_ < 3; ++p_) {
      uint32_t o = p_ * 4096 + so;
      uint32_t c = o / 384;  // local col
      *(f16x8*)(&wlds[0][0] + (o ^ ((c & 7) << 4))) = stg[p_];
    }
  }

#pragma unroll 1
  for (int t = 0; t < 18; ++t) {
    __syncthreads();  // buf[t&1] staged & visible; readers of buf[(t+1)&1] done
    const int cur = t & 1;

    // issue next-tile global loads EARLY (land during MFMAs)
    f16x8 stg[3];
    if (t < 17) {
#pragma unroll
      for (int p_ = 0; p_ < 3; ++p_)
        stg[p_] = *(const f16x8*)((const char*)W1 + (size_t)(t + 1) * 12288 +
                                  p_ * 4096 + so);
    }

    // W1 fragments from LDS (swizzle: byte ^ ((col&7)<<4); (16+L)&7 == L&7)
    const uint32_t sw = (uint32_t)(L & 7) << 4;
    f16x8 wf0[6], wf1[6];
#pragma unroll
    for (int kf = 0; kf < 6; ++kf) {
      uint32_t o0 = (uint32_t)L * 384 + (uint32_t)kf * 64 + (uint32_t)g * 16;
      wf0[kf] = *(const f16x8*)(&wlds[cur][0] + (o0 ^ sw));
      wf1[kf] = *(const f16x8*)(&wlds[cur][0] + ((o0 + 16 * 384) ^ sw));
    }

    f32x4 acc[2][2];
    acc[0][0] = (f32x4){0.f, 0.f, 0.f, 0.f}; acc[0][1] = acc[0][0];
    acc[1][0] = acc[0][0]; acc[1][1] = acc[0][0];
#pragma unroll
    for (int kf = 0; kf < 6; ++kf) {
      acc[0][0] = MFMA16(ax[0][kf], wf0[kf], acc[0][0]);
      acc[1][0] = MFMA16(ax[1][kf], wf0[kf], acc[1][0]);
      acc[0][1] = MFMA16(ax[0][kf], wf1[kf], acc[0][1]);
      acc[1][1] = MFMA16(ax[1][kf], wf1[kf], acc[1][1]);
    }

    // write staged tile into the other buffer (after MFMAs; loads are back)
    if (t < 17) {
#pragma unroll
      for (int p_ = 0; p_ < 3; ++p_) {
        uint32_t o = p_ * 4096 + so;
        uint32_t c = o / 384;
        *(f16x8*)(&wlds[cur ^ 1][0] + (o ^ ((c & 7) << 4))) = stg[p_];
      }
    }

    // ---- stores: s = t/6 (0:q 1:k 2:v), head hh = t%6, d = 16ct+L ----
    const int s = t / 6;           // wave-uniform
    const int tt = t - 6 * s;      // head index
    const float b0 = qkv_b[192 * s + 32 * tt + L];
    const float b1 = qkv_b[192 * s + 32 * tt + 16 + L];
    if (s < 2) {
      _Float16* dst = (s == 0) ? q16 : k16;
      const int off0 = tt * 1568 + L;
      const int off1 = tt * 1568 + 16 + L;
#pragma unroll
      for (int rt = 0; rt < 2; ++rt)
#pragma unroll
        for (int r = 0; r < 4; ++r) {
          dst[qkb[rt][r] + off0] = (_Float16)(acc[rt][0][r] + b0);
          dst[qkb[rt][r] + off1] = (_Float16)(acc[rt][1][r] + b1);
        }
    } else {
      const int off0 = tt * 1792 + L * 56;
      const int off1 = tt * 1792 + (16 + L) * 56;
#pragma unroll
      for (int rt = 0; rt < 2; ++rt)
#pragma unroll
        for (int r = 0; r < 4; ++r) {
          vt16[vtb[rt][r] + off0] = (_Float16)(acc[rt][0][r] + b0);
          vt16[vtb[rt][r] + off1] = (_Float16)(acc[rt][1][r] + b1);
        }
    }
  }
}

// ---------------- attention + proj, wave = head (unchanged from R7) --------
__global__ __launch_bounds__(384, 4) void k_attn2(
    const _Float16* __restrict__ q16, const _Float16* __restrict__ k16,
    const _Float16* __restrict__ vt16, const _Float16* __restrict__ bmi,
    const float* __restrict__ hsc, const _Float16* __restrict__ W2,
    const float* __restrict__ proj_b, float* __restrict__ out) {
  __shared__ __align__(16) _Float16 pl[6][16 * 72];  // per-wave P-hat
  __shared__ __align__(16) _Float16 ao[64 * 200];    // O staging [row][192+pad]

  const int b = blockIdx.x;
  const int tid = threadIdx.x;
  const int h = tid >> 6;
  const int lane = tid & 63;
  const int L = lane & 15;
  const int g = lane >> 4;

  const size_t qoff = ((size_t)b * NH + h) * 1568;  // 49*32
  const size_t voff = ((size_t)b * NH + h) * 1792;  // 32*56
  const float hs = hsc[h];

  f16x8 kf4[4];
#pragma unroll
  for (int jt = 0; jt < 4; ++jt) {
    int jrow = 16 * jt + L; if (jrow > 48) jrow = 48;
    kf4[jt] = *(const f16x8*)(k16 + qoff + jrow * 32 + 8 * g);
  }
  f16x8 vf[2][2];
#pragma unroll
  for (int dt = 0; dt < 2; ++dt)
#pragma unroll
    for (int kf = 0; kf < 2; ++kf) {
      int joff = 32 * kf + 8 * g; if (joff > 48) joff = 48;
      vf[dt][kf] = *(const f16x8*)(vt16 + voff + (16 * dt + L) * 56 + joff);
    }

  float krr[4][4];
#pragma unroll
  for (int jt = 0; jt < 4; ++jt) {
    float kk = 0.f;
#pragma unroll
    for (int e = 0; e < 8; ++e) kk += (float)kf4[jt][e] * (float)kf4[jt][e];
    kk += __shfl_xor(kk, 16);
    kk += __shfl_xor(kk, 32);
#pragma unroll
    for (int r = 0; r < 4; ++r)
      krr[jt][r] = rsqrtf(fmaxf(__shfl(kk, 4 * g + r, 64), 1e-24f));
  }

  _Float16* plw = &pl[h][0];
  const _Float16* bmp = bmi + ((size_t)(b & 63) * NH + h) * 2548;

#pragma unroll 1
  for (int it = 0; it < 4; ++it) {
    int irow = 16 * it + L; if (irow > 48) irow = 48;
    f16x8 qf = *(const f16x8*)(q16 + qoff + irow * 32 + 8 * g);
    float qq = 0.f;
#pragma unroll
    for (int e = 0; e < 8; ++e) qq += (float)qf[e] * (float)qf[e];
    qq += __shfl_xor(qq, 16);
    qq += __shfl_xor(qq, 32);
    const float qr = rsqrtf(fmaxf(qq, 1e-24f)) * hs;

    f32x4 st[4];
#pragma unroll
    for (int jt = 0; jt < 4; ++jt) {
      f32x4 z = {0.f, 0.f, 0.f, 0.f};
      st[jt] = MFMA16(kf4[jt], qf, z);
    }
    const _Float16* bp = bmp + (16 * it + L) * 52 + 4 * g;
    float p[4][4];
#pragma unroll
    for (int jt = 0; jt < 4; ++jt) {
      f16x4h bm4 = *(const f16x4h*)(bp + 16 * jt);
#pragma unroll
      for (int r = 0; r < 4; ++r) {
        int j = 16 * jt + 4 * g + r;
        p[jt][r] = (j < NTOK)
                       ? fmaf(st[jt][r], qr * krr[jt][r], (float)bm4[r])
                       : -1e30f;
      }
    }
    float mx = p[0][0];
#pragma unroll
    for (int jt = 0; jt < 4; ++jt)
#pragma unroll
      for (int r = 0; r < 4; ++r) mx = fmaxf(mx, p[jt][r]);
    mx = fmaxf(mx, __shfl_xor(mx, 16));
    mx = fmaxf(mx, __shfl_xor(mx, 32));
    float sum = 0.f;
#pragma unroll
    for (int jt = 0; jt < 4; ++jt)
#pragma unroll
      for (int r = 0; r < 4; ++r) {
        p[jt][r] = __expf(p[jt][r] - mx);
        sum += p[jt][r];
      }
    sum += __shfl_xor(sum, 16);
    sum += __shfl_xor(sum, 32);
    const float is = 1.0f / sum;

#pragma unroll
    for (int jt = 0; jt < 4; ++jt) {
      f16x4h pk;
#pragma unroll
      for (int r = 0; r < 4; ++r) pk[r] = (_Float16)(p[jt][r] * is);
      *(f16x4h*)(plw + L * 72 + 16 * jt + 4 * g) = pk;
    }
    f16x8 pa0 = *(const f16x8*)(plw + L * 72 + 8 * g);
    f16x8 pa1 = *(const f16x8*)(plw + L * 72 + 32 + 8 * g);
#pragma unroll
    for (int dt = 0; dt < 2; ++dt) {
      f32x4 o4 = {0.f, 0.f, 0.f, 0.f};
      o4 = MFMA16(pa0, vf[dt][0], o4);
      o4 = MFMA16(pa1, vf[dt][1], o4);
#pragma unroll
      for (int r = 0; r < 4; ++r)
        ao[(16 * it + 4 * g + r) * 200 + 32 * h + 16 * dt + L] = (_Float16)o4[r];
    }
  }
  __syncthreads();  // the ONLY barrier

#pragma unroll
  for (int cp = 0; cp < 2; ++cp) {
    const int ct = h + 6 * cp;
    const _Float16* wp = W2 + (size_t)(16 * ct + L) * DIM + 8 * g;
    f16x8 wfr[6];
#pragma unroll
    for (int kf = 0; kf < 6; ++kf) wfr[kf] = *(const f16x8*)(wp + 32 * kf);
    const float pbv = proj_b[16 * ct + L];
#pragma unroll 1
    for (int mt = 0; mt < 4; ++mt) {
      f32x4 acc = {0.f, 0.f, 0.f, 0.f};
#pragma unroll
      for (int kf = 0; kf < 6; ++kf) {
        f16x8 af = *(const f16x8*)(ao + (16 * mt + L) * 200 + 32 * kf + 8 * g);
        acc = MFMA16(af, wfr[kf], acc);
      }
#pragma unroll
      for (int r = 0; r < 4; ++r) {
        int row = 16 * mt + 4 * g + r;
        if (row < NTOK)
          out[((size_t)b * NTOK + row) * DIM + 16 * ct + L] = acc[r] + pbv;
      }
    }
  }
}

extern "C" void kernel_launch(void* const* d_in, const int* in_sizes, int n_in,
                              void* d_out, int out_size, void* d_ws, size_t ws_size,
                              hipStream_t stream) {
  const float* x     = (const float*)d_in[0];
  const float* mask  = (const float*)d_in[1];
  const float* qkv_w = (const float*)d_in[2];
  const float* qkv_b = (const float*)d_in[3];
  const float* ls    = (const float*)d_in[4];
  const float* tbl   = (const float*)d_in[5];
  const int*   ridx  = (const int*)d_in[6];
  const float* pw    = (const float*)d_in[7];
  const float* pb    = (const float*)d_in[8];
  float* out = (float*)d_out;
  char* ws = (char*)d_ws;

  _Float16* W1 = (_Float16*)(ws + W1_OFF);
  _Float16* W2 = (_Float16*)(ws + W2_OFF);
  _Float16* bmi = (_Float16*)(ws + BMI_OFF);
  float* hsc = (float*)(ws + HSC_OFF);
  _Float16* q16 = (_Float16*)(ws + Q_OFF);
  _Float16* k16 = (_Float16*)(ws + K_OFF);
  _Float16* vt16 = (_Float16*)(ws + VT_OFF);

  hipLaunchKernelGGL(k_setup, dim3(3602), dim3(256), 0, stream,
                     qkv_w, pw, mask, tbl, ridx, ls, W1, W2, bmi, hsc);
  hipLaunchKernelGGL(k_qkv, dim3(MTOT / 128), dim3(256), 0, stream,
                     x, W1, qkv_b, q16, k16, vt16);
  hipLaunchKernelGGL(k_attn2, dim3(BATCH), dim3(384), 0, stream,
                     q16, k16, vt16, bmi, hsc, W2, pb, out);
}

// Round 9
// 301.971 us; speedup vs baseline: 2.3526x; 1.0198x over previous
//
#include <hip/hip_runtime.h>
#include <hip/hip_fp16.h>

// Swin-V2 window attention, MI355X (gfx950). Round 9.
// k_qkv v3: 256 rows/block (rt=4, 48 MFMA/wave/K-step), W1 staged in
//   3-tile LDS groups (72KB dbuf, XOR swizzle) -> only 6 barriers/block
//   (each __syncthreads drains stores: was the R8 serializer). v now stored
//   row-major like q/k (kills the 112B-stride scatter store).
// k_attn2: V^T fragments via 32 clamped scalar u16 loads; rest = R8.

#define NTOK 49
#define DIM 192
#define NH 6
#define BATCH 4096
#define MTOT 200704  // BATCH*NTOK

typedef __attribute__((ext_vector_type(4))) float f32x4;
typedef __attribute__((ext_vector_type(8))) _Float16 f16x8;
typedef __attribute__((ext_vector_type(4))) _Float16 f16x4h;

// ws layout (bytes)
#define W1_OFF 0                 // [576][192] f16
#define W2_OFF 221184            // [192][192] f16
#define BMI_OFF 294912           // [64*6][49 x 52] f16 (+slack)
#define HSC_OFF 2260992          // [6] f32
#define Q_OFF 4194304            // [B][6][49][32] f16 = 77.1 MB
#define K_OFF 81264640           // same
#define V_OFF 158334976          // same layout as q/k now (end ~235.4MB)

#define MFMA16(a, b, c) __builtin_amdgcn_mfma_f32_16x16x32_f16(a, b, c, 0, 0, 0)

__global__ __launch_bounds__(256) void k_setup(
    const float* __restrict__ qkv_w, const float* __restrict__ proj_w,
    const float* __restrict__ mask, const float* __restrict__ table,
    const int* __restrict__ rel_index, const float* __restrict__ ls,
    _Float16* __restrict__ W1, _Float16* __restrict__ W2,
    _Float16* __restrict__ bmi, float* __restrict__ hsc) {
  int idx = blockIdx.x * 256 + threadIdx.x;
  if (idx < 576 * 192) W1[idx] = (_Float16)qkv_w[idx];
  if (idx < 192 * 192) W2[idx] = (_Float16)proj_w[idx];
  if (idx < NH) hsc[idx] = __expf(fminf(ls[idx], 4.60517019f));
  if (idx < 64 * NH * 2401) {
    int p = idx / 2401, rem = idx % 2401;
    int i = rem / 49, j = rem % 49;  // stored [p][i (stride 52)][j]
    int wdx = p / NH, h = p % NH;
    bmi[(size_t)p * 2548 + i * 52 + j] =
        (_Float16)(table[rel_index[i * 49 + j] * NH + h] +
                   mask[wdx * 2401 + i * 49 + j]);
  }
}

// ---------------- QKV GEMM: 256 rows/block, 3-tile LDS groups ----------------
__global__ __launch_bounds__(256, 2) void k_qkv(
    const float* __restrict__ x, const _Float16* __restrict__ W1,
    const float* __restrict__ qkv_b, _Float16* __restrict__ q16,
    _Float16* __restrict__ k16, _Float16* __restrict__ v16) {
  __shared__ __align__(16) char wlds[2][36864];  // 3 x 32-col W1 tiles, swizzled

  const int tid = threadIdx.x;
  const int lane = tid & 63;
  const int w = tid >> 6;
  const int rowbase = blockIdx.x * 256 + w * 64;
  const int L = lane & 15;
  const int g = lane >> 4;

  // A fragments: 4 row-tiles x 6 K-frags (f32 x -> f16)
  f16x8 ax[4][6];
#pragma unroll
  for (int rt = 0; rt < 4; ++rt) {
    const float* xr = x + (size_t)(rowbase + rt * 16 + L) * DIM + 8 * g;
#pragma unroll
    for (int kf = 0; kf < 6; ++kf) {
      f32x4 lo = *(const f32x4*)(xr + 32 * kf);
      f32x4 hi = *(const f32x4*)(xr + 32 * kf + 4);
      f16x8 v;
      v[0] = (_Float16)lo[0]; v[1] = (_Float16)lo[1];
      v[2] = (_Float16)lo[2]; v[3] = (_Float16)lo[3];
      v[4] = (_Float16)hi[0]; v[5] = (_Float16)hi[1];
      v[6] = (_Float16)hi[2]; v[7] = (_Float16)hi[3];
      ax[rt][kf] = v;
    }
  }
  // row meta (all q/k/v share the [B][6][49][32] layout now)
  int qkb[4][4];
#pragma unroll
  for (int rt = 0; rt < 4; ++rt)
#pragma unroll
    for (int r = 0; r < 4; ++r) {
      int row = rowbase + rt * 16 + 4 * g + r;
      int bb = row / 49, n = row - bb * 49;
      qkb[rt][r] = bb * 9408 + n * 32;  // + h*1568 + d
    }

  const uint32_t so = (uint32_t)tid * 16;  // per-thread 16B staging slot

  // ---- prologue: stage group 0 (tiles 0..2) into buf 0 ----
  {
    f16x8 stg[9];
#pragma unroll
    for (int p_ = 0; p_ < 9; ++p_)
      stg[p_] = *(const f16x8*)((const char*)W1 + p_ * 4096 + so);
#pragma unroll
    for (int p_ = 0; p_ < 9; ++p_) {
      uint32_t o = (uint32_t)(p_ % 3) * 4096 + so;
      uint32_t c = o / 384;
      *(f16x8*)(&wlds[0][(p_ / 3) * 12288 + (o ^ ((c & 7) << 4))]) = stg[p_];
    }
  }

#pragma unroll 1
  for (int grp = 0; grp < 6; ++grp) {
    __syncthreads();
    const int cur = grp & 1;

    // issue next-group global loads EARLY (land during 144 MFMAs)
    f16x8 stg[9];
    if (grp < 5) {
#pragma unroll
      for (int p_ = 0; p_ < 9; ++p_)
        stg[p_] = *(const f16x8*)((const char*)W1 + (size_t)(grp + 1) * 36864 +
                                  p_ * 4096 + so);
    }

    const uint32_t sw = (uint32_t)(L & 7) << 4;
#pragma unroll
    for (int tl = 0; tl < 3; ++tl) {
      const int t = grp * 3 + tl;
      const int s = t / 6;           // 0:q 1:k 2:v (wave-uniform)
      const int tt = t - 6 * s;      // head
      _Float16* dst = (s == 0) ? q16 : (s == 1) ? k16 : v16;
      const char* base = &wlds[cur][tl * 12288];
#pragma unroll
      for (int ct = 0; ct < 2; ++ct) {
        f16x8 wf[6];
#pragma unroll
        for (int kf = 0; kf < 6; ++kf) {
          uint32_t o0 = (uint32_t)(16 * ct + L) * 384 + (uint32_t)kf * 64 +
                        (uint32_t)g * 16;
          wf[kf] = *(const f16x8*)(base + (o0 ^ sw));
        }
        f32x4 acc[4];
#pragma unroll
        for (int rt = 0; rt < 4; ++rt) acc[rt] = (f32x4){0.f, 0.f, 0.f, 0.f};
#pragma unroll
        for (int kf = 0; kf < 6; ++kf)
#pragma unroll
          for (int rt = 0; rt < 4; ++rt)
            acc[rt] = MFMA16(ax[rt][kf], wf[kf], acc[rt]);
        const float bias = qkv_b[192 * s + 32 * tt + 16 * ct + L];
        const int off = tt * 1568 + 16 * ct + L;
#pragma unroll
        for (int rt = 0; rt < 4; ++rt)
#pragma unroll
          for (int r = 0; r < 4; ++r)
            dst[qkb[rt][r] + off] = (_Float16)(acc[rt][r] + bias);
      }
    }

    // write staged group into the other buffer (write-late)
    if (grp < 5) {
#pragma unroll
      for (int p_ = 0; p_ < 9; ++p_) {
        uint32_t o = (uint32_t)(p_ % 3) * 4096 + so;
        uint32_t c = o / 384;
        *(f16x8*)(&wlds[cur ^ 1][(p_ / 3) * 12288 + (o ^ ((c & 7) << 4))]) =
            stg[p_];
      }
    }
  }
}

// ---------------- attention + proj, wave = head ----------------
__global__ __launch_bounds__(384, 4) void k_attn2(
    const _Float16* __restrict__ q16, const _Float16* __restrict__ k16,
    const _Float16* __restrict__ v16, const _Float16* __restrict__ bmi,
    const float* __restrict__ hsc, const _Float16* __restrict__ W2,
    const float* __restrict__ proj_b, float* __restrict__ out) {
  __shared__ __align__(16) _Float16 pl[6][16 * 72];  // per-wave P-hat
  __shared__ __align__(16) _Float16 ao[64 * 200];    // O staging [row][192+pad]

  const int b = blockIdx.x;
  const int tid = threadIdx.x;
  const int h = tid >> 6;
  const int lane = tid & 63;
  const int L = lane & 15;
  const int g = lane >> 4;

  const size_t qoff = ((size_t)b * NH + h) * 1568;  // 49*32
  const float hs = hsc[h];

  // V^T B-fragments: 32 scalar u16 loads (4x32B sectors/instr), clamped.
  // Clamped/overrun j-slots multiply P-hat slots that are exactly 0.
  f16x8 vf[2][2];
#pragma unroll
  for (int dt = 0; dt < 2; ++dt)
#pragma unroll
    for (int kf = 0; kf < 2; ++kf)
#pragma unroll
      for (int e = 0; e < 8; ++e) {
        int j = 32 * kf + 8 * g + e;
        if (j > 48) j = 48;
        vf[dt][kf][e] = v16[qoff + j * 32 + 16 * dt + L];
      }

  f16x8 kf4[4];
#pragma unroll
  for (int jt = 0; jt < 4; ++jt) {
    int jrow = 16 * jt + L; if (jrow > 48) jrow = 48;
    kf4[jt] = *(const f16x8*)(k16 + qoff + jrow * 32 + 8 * g);
  }

  float krr[4][4];
#pragma unroll
  for (int jt = 0; jt < 4; ++jt) {
    float kk = 0.f;
#pragma unroll
    for (int e = 0; e < 8; ++e) kk += (float)kf4[jt][e] * (float)kf4[jt][e];
    kk += __shfl_xor(kk, 16);
    kk += __shfl_xor(kk, 32);
#pragma unroll
    for (int r = 0; r < 4; ++r)
      krr[jt][r] = rsqrtf(fmaxf(__shfl(kk, 4 * g + r, 64), 1e-24f));
  }

  _Float16* plw = &pl[h][0];
  const _Float16* bmp = bmi + ((size_t)(b & 63) * NH + h) * 2548;

#pragma unroll 1
  for (int it = 0; it < 4; ++it) {
    int irow = 16 * it + L; if (irow > 48) irow = 48;
    f16x8 qf = *(const f16x8*)(q16 + qoff + irow * 32 + 8 * g);
    float qq = 0.f;
#pragma unroll
    for (int e = 0; e < 8; ++e) qq += (float)qf[e] * (float)qf[e];
    qq += __shfl_xor(qq, 16);
    qq += __shfl_xor(qq, 32);
    const float qr = rsqrtf(fmaxf(qq, 1e-24f)) * hs;

    f32x4 st[4];
#pragma unroll
    for (int jt = 0; jt < 4; ++jt) {
      f32x4 z = {0.f, 0.f, 0.f, 0.f};
      st[jt] = MFMA16(kf4[jt], qf, z);
    }
    const _Float16* bp = bmp + (16 * it + L) * 52 + 4 * g;
    float p[4][4];
#pragma unroll
    for (int jt = 0; jt < 4; ++jt) {
      f16x4h bm4 = *(const f16x4h*)(bp + 16 * jt);
#pragma unroll
      for (int r = 0; r < 4; ++r) {
        int j = 16 * jt + 4 * g + r;
        p[jt][r] = (j < NTOK)
                       ? fmaf(st[jt][r], qr * krr[jt][r], (float)bm4[r])
                       : -1e30f;
      }
    }
    float mx = p[0][0];
#pragma unroll
    for (int jt = 0; jt < 4; ++jt)
#pragma unroll
      for (int r = 0; r < 4; ++r) mx = fmaxf(mx, p[jt][r]);
    mx = fmaxf(mx, __shfl_xor(mx, 16));
    mx = fmaxf(mx, __shfl_xor(mx, 32));
    float sum = 0.f;
#pragma unroll
    for (int jt = 0; jt < 4; ++jt)
#pragma unroll
      for (int r = 0; r < 4; ++r) {
        p[jt][r] = __expf(p[jt][r] - mx);
        sum += p[jt][r];
      }
    sum += __shfl_xor(sum, 16);
    sum += __shfl_xor(sum, 32);
    const float is = 1.0f / sum;

#pragma unroll
    for (int jt = 0; jt < 4; ++jt) {
      f16x4h pk;
#pragma unroll
      for (int r = 0; r < 4; ++r) pk[r] = (_Float16)(p[jt][r] * is);
      *(f16x4h*)(plw + L * 72 + 16 * jt + 4 * g) = pk;
    }
    f16x8 pa0 = *(const f16x8*)(plw + L * 72 + 8 * g);
    f16x8 pa1 = *(const f16x8*)(plw + L * 72 + 32 + 8 * g);
#pragma unroll
    for (int dt = 0; dt < 2; ++dt) {
      f32x4 o4 = {0.f, 0.f, 0.f, 0.f};
      o4 = MFMA16(pa0, vf[dt][0], o4);
      o4 = MFMA16(pa1, vf[dt][1], o4);
#pragma unroll
      for (int r = 0; r < 4; ++r)
        ao[(16 * it + 4 * g + r) * 200 + 32 * h + 16 * dt + L] = (_Float16)o4[r];
    }
  }
  __syncthreads();  // the ONLY barrier

#pragma unroll
  for (int cp = 0; cp < 2; ++cp) {
    const int ct = h + 6 * cp;
    const _Float16* wp = W2 + (size_t)(16 * ct + L) * DIM + 8 * g;
    f16x8 wfr[6];
#pragma unroll
    for (int kf = 0; kf < 6; ++kf) wfr[kf] = *(const f16x8*)(wp + 32 * kf);
    const float pbv = proj_b[16 * ct + L];
#pragma unroll 1
    for (int mt = 0; mt < 4; ++mt) {
      f32x4 acc = {0.f, 0.f, 0.f, 0.f};
#pragma unroll
      for (int kf = 0; kf < 6; ++kf) {
        f16x8 af = *(const f16x8*)(ao + (16 * mt + L) * 200 + 32 * kf + 8 * g);
        acc = MFMA16(af, wfr[kf], acc);
      }
#pragma unroll
      for (int r = 0; r < 4; ++r) {
        int row = 16 * mt + 4 * g + r;
        if (row < NTOK)
          out[((size_t)b * NTOK + row) * DIM + 16 * ct + L] = acc[r] + pbv;
      }
    }
  }
}

extern "C" void kernel_launch(void* const* d_in, const int* in_sizes, int n_in,
                              void* d_out, int out_size, void* d_ws, size_t ws_size,
                              hipStream_t stream) {
  const float* x     = (const float*)d_in[0];
  const float* mask  = (const float*)d_in[1];
  const float* qkv_w = (const float*)d_in[2];
  const float* qkv_b = (const float*)d_in[3];
  const float* ls    = (const float*)d_in[4];
  const float* tbl   = (const float*)d_in[5];
  const int*   ridx  = (const int*)d_in[6];
  const float* pw    = (const float*)d_in[7];
  const float* pb    = (const float*)d_in[8];
  float* out = (float*)d_out;
  char* ws = (char*)d_ws;

  _Float16* W1 = (_Float16*)(ws + W1_OFF);
  _Float16* W2 = (_Float16*)(ws + W2_OFF);
  _Float16* bmi = (_Float16*)(ws + BMI_OFF);
  float* hsc = (float*)(ws + HSC_OFF);
  _Float16* q16 = (_Float16*)(ws + Q_OFF);
  _Float16* k16 = (_Float16*)(ws + K_OFF);
  _Float16* v16 = (_Float16*)(ws + V_OFF);

  hipLaunchKernelGGL(k_setup, dim3(3602), dim3(256), 0, stream,
                     qkv_w, pw, mask, tbl, ridx, ls, W1, W2, bmi, hsc);
  hipLaunchKernelGGL(k_qkv, dim3(MTOT / 256), dim3(256), 0, stream,
                     x, W1, qkv_b, q16, k16, v16);
  hipLaunchKernelGGL(k_attn2, dim3(BATCH), dim3(384), 0, stream,
                     q16, k16, v16, bmi, hsc, W2, pb, out);
}